// Round 1
// 248.066 us; speedup vs baseline: 1.0928x; 1.0928x over previous
//
#include <hip/hip_runtime.h>
#include <stdint.h>

#define K_DIM 4096
#define N_DIM 4096
#define SIGMA 20.0f
#define EPSQ 1e-8f

typedef __attribute__((ext_vector_type(4))) int i32x4;

// global_load_lds width-16 helper (addrspace casts: generic->AS1 / ->AS3)
#define GLDS16(gp, lp)                                                         \
  __builtin_amdgcn_global_load_lds(                                            \
      (const __attribute__((address_space(1))) unsigned int*)(const void*)(gp),\
      (__attribute__((address_space(3))) unsigned int*)(void*)(lp), 16, 0, 0)

// ---------------------------------------------------------------------------
// Kernel 1: per-row absmax -> row_scale, outlier column mask, quantize x->int8
// ---------------------------------------------------------------------------
__global__ __launch_bounds__(256) void k_rowquant(
    const float* __restrict__ x, float* __restrict__ row_scale,
    int* __restrict__ mask, int8_t* __restrict__ qx)
{
  const int m = blockIdx.x;
  const int t = threadIdx.x;
  const float4* xr = (const float4*)(x + (size_t)m * K_DIM);
  float4 v[4];
  float amax = 0.0f;
#pragma unroll
  for (int i = 0; i < 4; ++i) {
    v[i] = xr[t + i * 256];
    float a0 = fabsf(v[i].x), a1 = fabsf(v[i].y);
    float a2 = fabsf(v[i].z), a3 = fabsf(v[i].w);
    amax = fmaxf(amax, fmaxf(fmaxf(a0, a1), fmaxf(a2, a3)));
    int kbase = (t + i * 256) * 4;
    if (a0 > SIGMA) mask[kbase + 0] = 1;
    if (a1 > SIGMA) mask[kbase + 1] = 1;
    if (a2 > SIGMA) mask[kbase + 2] = 1;
    if (a3 > SIGMA) mask[kbase + 3] = 1;
  }
#pragma unroll
  for (int off = 32; off > 0; off >>= 1)
    amax = fmaxf(amax, __shfl_down(amax, off, 64));
  __shared__ float smax[4];
  __shared__ float sscale;
  if ((t & 63) == 0) smax[t >> 6] = amax;
  __syncthreads();
  if (t == 0) {
    float ms = fmaxf(fmaxf(smax[0], smax[1]), fmaxf(smax[2], smax[3]));
    float rs = fmaxf(ms / 127.0f, EPSQ);  // IEEE divide: bit-match jnp
    sscale = rs;
    row_scale[m] = rs;
  }
  __syncthreads();
  const float rs = sscale;
  uint32_t* qxo = (uint32_t*)(qx + (size_t)m * K_DIM);
#pragma unroll
  for (int i = 0; i < 4; ++i) {
    int q0 = (int)rintf(fminf(fmaxf(v[i].x / rs, -128.0f), 127.0f));
    int q1 = (int)rintf(fminf(fmaxf(v[i].y / rs, -128.0f), 127.0f));
    int q2 = (int)rintf(fminf(fmaxf(v[i].z / rs, -128.0f), 127.0f));
    int q3 = (int)rintf(fminf(fmaxf(v[i].w / rs, -128.0f), 127.0f));
    uint32_t packed = (uint32_t)(q0 & 0xff) | ((uint32_t)(q1 & 0xff) << 8) |
                      ((uint32_t)(q2 & 0xff) << 16) | ((uint32_t)(q3 & 0xff) << 24);
    qxo[t + i * 256] = packed;
  }
}

// ---------------------------------------------------------------------------
// Kernel 2: compact mask -> outlier column list + count
// ---------------------------------------------------------------------------
__global__ __launch_bounds__(256) void k_compact(
    const int* __restrict__ mask, int* __restrict__ outlist,
    int* __restrict__ count)
{
  int k = blockIdx.x * 256 + threadIdx.x;
  if (mask[k]) {
    int idx = atomicAdd(count, 1);
    outlist[idx] = k;
  }
}

// ---------------------------------------------------------------------------
// Kernel 3: weight quant: zero outlier cols, per-row absmax -> q_scale, int8
// ---------------------------------------------------------------------------
__global__ __launch_bounds__(256) void k_wquant(
    const float* __restrict__ w, const int* __restrict__ mask,
    float* __restrict__ q_scale, int8_t* __restrict__ qw)
{
  const int n = blockIdx.x;
  const int t = threadIdx.x;
  const float4* wr = (const float4*)(w + (size_t)n * K_DIM);
  const int4* mr = (const int4*)mask;
  float4 v[4];
  float amax = 0.0f;
#pragma unroll
  for (int i = 0; i < 4; ++i) {
    float4 vv = wr[t + i * 256];
    int4 mm = mr[t + i * 256];
    vv.x = mm.x ? 0.0f : vv.x;
    vv.y = mm.y ? 0.0f : vv.y;
    vv.z = mm.z ? 0.0f : vv.z;
    vv.w = mm.w ? 0.0f : vv.w;
    v[i] = vv;
    amax = fmaxf(amax, fmaxf(fmaxf(fabsf(vv.x), fabsf(vv.y)),
                             fmaxf(fabsf(vv.z), fabsf(vv.w))));
  }
#pragma unroll
  for (int off = 32; off > 0; off >>= 1)
    amax = fmaxf(amax, __shfl_down(amax, off, 64));
  __shared__ float smax[4];
  __shared__ float sscale;
  if ((t & 63) == 0) smax[t >> 6] = amax;
  __syncthreads();
  if (t == 0) {
    float ms = fmaxf(fmaxf(smax[0], smax[1]), fmaxf(smax[2], smax[3]));
    float qs = fmaxf(ms / 127.0f, EPSQ);
    sscale = qs;
    q_scale[n] = qs;
  }
  __syncthreads();
  const float qs = sscale;
  uint32_t* qwo = (uint32_t*)(qw + (size_t)n * K_DIM);
#pragma unroll
  for (int i = 0; i < 4; ++i) {
    int q0 = (int)rintf(fminf(fmaxf(v[i].x / qs, -128.0f), 127.0f));
    int q1 = (int)rintf(fminf(fmaxf(v[i].y / qs, -128.0f), 127.0f));
    int q2 = (int)rintf(fminf(fmaxf(v[i].z / qs, -128.0f), 127.0f));
    int q3 = (int)rintf(fminf(fmaxf(v[i].w / qs, -128.0f), 127.0f));
    uint32_t packed = (uint32_t)(q0 & 0xff) | ((uint32_t)(q1 & 0xff) << 8) |
                      ((uint32_t)(q2 & 0xff) << 16) | ((uint32_t)(q3 & 0xff) << 24);
    qwo[t + i * 256] = packed;
  }
}

// ---------------------------------------------------------------------------
// Kernel 4: int8 GEMM, 256x256 tile, BK=64, 8 waves (2Mx4N), 512 threads.
// Counted-vmcnt deep pipeline (T3+T4): 4 LDS tile buffers (128 KB), stage
// tile t+3 while computing tile t, s_waitcnt vmcnt(8) once per K-tile
// (never 0 in the main loop). Raw s_barrier + asm lgkmcnt(0) +
// sched_barrier(0) per rule #18; s_setprio(1) around MFMA clusters (T5).
// 64B LDS rows with 2-row-unit XOR chunk swizzle c_phys = c ^ ((row>>1)&3)
// (conflict-free quarter-wave ds_read_b128; same swizzle valid for row+128
// since 128/2 ≡ 0 mod 4). Swizzle applied on the GLOBAL source side (GLDS
// dest must stay base + lane*16) and on precomputed LDS read offsets.
// Loop stages (kt+3)%64 unconditionally: wrap loads are redundant-but-
// harmless and keep vmcnt counts uniform (no epilogue drain special-case).
// ---------------------------------------------------------------------------
__global__ __launch_bounds__(512, 2) void k_gemm(
    const int8_t* __restrict__ qx, const int8_t* __restrict__ qw,
    const float* __restrict__ row_scale, const float* __restrict__ q_scale,
    const float* __restrict__ bias,
    const float* __restrict__ x, const float* __restrict__ w,
    const int* __restrict__ outlist, const int* __restrict__ outcount,
    float* __restrict__ out)
{
  __shared__ int8_t As[4][256 * 64];   // 4 x 16 KB
  __shared__ int8_t Bs[4][256 * 64];   // 4 x 16 KB   -> 128 KB total

  const int t = threadIdx.x;            // 0..511
  const int m0 = blockIdx.y * 256;
  const int n0 = blockIdx.x * 256;
  const int lane = t & 63;
  const int wave = t >> 6;              // 0..7
  const int wm = (wave >> 2) * 128;     // 0 or 128
  const int wn = (wave & 3) * 64;       // 0,64,128,192
  const int lrow = lane & 15;
  const int kg = lane >> 4;             // 0..3

  i32x4 acc[8][4] = {};

  // staging: thread t covers row t>>2 (0..127 within half-tile), phys chunk t&3
  const int srow = t >> 2;
  const int sclog = (t & 3) ^ ((srow >> 1) & 3);
  const int8_t* gA = qx + (size_t)(m0 + srow) * K_DIM + sclog * 16;
  const int8_t* gB = qw + (size_t)(n0 + srow) * K_DIM + sclog * 16;

  // loop-invariant swizzled LDS read offsets (within one 16 KB tile buffer)
  int offA[8], offB[4];
#pragma unroll
  for (int i = 0; i < 8; ++i) {
    int rA = wm + i * 16 + lrow;
    offA[i] = rA * 64 + ((kg ^ ((rA >> 1) & 3)) * 16);
  }
#pragma unroll
  for (int j = 0; j < 4; ++j) {
    int rB = wn + j * 16 + lrow;
    offB[j] = rB * 64 + ((kg ^ ((rB >> 1) & 3)) * 16);
  }

#define STAGE_A(b, tt) do {                                                    \
    GLDS16(gA + (size_t)(tt) * 64, &As[b][t * 16]);                            \
    GLDS16(gA + (size_t)128 * K_DIM + (size_t)(tt) * 64, &As[b][8192 + t * 16]);\
  } while (0)
#define STAGE_B(b, tt) do {                                                    \
    GLDS16(gB + (size_t)(tt) * 64, &Bs[b][t * 16]);                            \
    GLDS16(gB + (size_t)128 * K_DIM + (size_t)(tt) * 64, &Bs[b][8192 + t * 16]);\
  } while (0)

  // prologue: fill 3 tiles (12 gloads/wave); wait only tile 0 (newest 8 in flight)
  STAGE_A(0, 0); STAGE_B(0, 0);
  STAGE_A(1, 1); STAGE_B(1, 1);
  STAGE_A(2, 2); STAGE_B(2, 2);
  asm volatile("s_waitcnt vmcnt(8)" ::: "memory");
  __builtin_amdgcn_s_barrier();

#pragma unroll 4
  for (int kt = 0; kt < 64; ++kt) {
    const int cur = kt & 3;
    const int nx = (kt + 3) & 3;        // == (kt-1)&3: fully consumed last tile
    const int ktn = (kt + 3) & 63;      // wrap staging keeps vmcnt uniform
    const int8_t* a = &As[cur][0];
    const int8_t* b = &Bs[cur][0];

    // ---- phase 1: read A-top + all B, stage next A, compute top half ----
    i32x4 af[4], bf[4];
#pragma unroll
    for (int i = 0; i < 4; ++i) af[i] = *(const i32x4*)(a + offA[i]);
#pragma unroll
    for (int j = 0; j < 4; ++j) bf[j] = *(const i32x4*)(b + offB[j]);
    STAGE_A(nx, ktn);
    __builtin_amdgcn_s_barrier();
    asm volatile("s_waitcnt lgkmcnt(0)" ::: "memory");
    __builtin_amdgcn_sched_barrier(0);
    __builtin_amdgcn_s_setprio(1);
#pragma unroll
    for (int i = 0; i < 4; ++i)
#pragma unroll
      for (int j = 0; j < 4; ++j)
        acc[i][j] = __builtin_amdgcn_mfma_i32_16x16x64_i8(af[i], bf[j], acc[i][j], 0, 0, 0);
    __builtin_amdgcn_s_setprio(0);
    __builtin_amdgcn_s_barrier();

    // ---- phase 2: read A-bot (B reused in regs), stage next B, bottom half ----
    i32x4 af2[4];
#pragma unroll
    for (int i = 0; i < 4; ++i) af2[i] = *(const i32x4*)(a + offA[4 + i]);
    STAGE_B(nx, ktn);
    __builtin_amdgcn_s_barrier();
    asm volatile("s_waitcnt lgkmcnt(0)" ::: "memory");
    __builtin_amdgcn_sched_barrier(0);
    __builtin_amdgcn_s_setprio(1);
#pragma unroll
    for (int i = 0; i < 4; ++i)
#pragma unroll
      for (int j = 0; j < 4; ++j)
        acc[4 + i][j] = __builtin_amdgcn_mfma_i32_16x16x64_i8(af2[i], bf[j], acc[4 + i][j], 0, 0, 0);
    __builtin_amdgcn_s_setprio(0);
    // counted wait: tiles kt+2,kt+3 (8 loads) may stay in flight; kt+1 is ready
    asm volatile("s_waitcnt vmcnt(8)" ::: "memory");
    __builtin_amdgcn_s_barrier();
  }

#undef STAGE_A
#undef STAGE_B

  // ---- epilogue: stage outlier x / w slices into LDS (reuse buffer 0) ----
  __syncthreads();  // drains stray wrap-around gloads (they target bufs 1,2 only)
  float* xsh = (float*)&As[0][0];   // [256][8]
  float* wsh = (float*)&Bs[0][0];   // [256][8]
  const int cnt = *outcount;
  const int cs = cnt < 8 ? cnt : 8;
#pragma unroll
  for (int u = 0; u < 4; ++u) {
    int idx = t * 4 + u;   // 0..2047
    int rr = idx >> 3;     // 0..255
    int oo = idx & 7;
    float xv = 0.0f, wv = 0.0f;
    if (oo < cs) {
      int kcol = outlist[oo];
      xv = x[(size_t)(m0 + rr) * K_DIM + kcol];
      wv = w[(size_t)(n0 + rr) * K_DIM + kcol];
    }
    xsh[rr * 8 + oo] = xv;
    wsh[rr * 8 + oo] = wv;
  }
  __syncthreads();

  float qs[4], bv[4];
  int gn[4];
#pragma unroll
  for (int j = 0; j < 4; ++j) {
    gn[j] = n0 + wn + j * 16 + lrow;
    qs[j] = q_scale[gn[j]];
    bv[j] = bias[gn[j]];
  }

  // C/D layout: col = lane&15, row = (lane>>4)*4 + reg  [m89/m101, dtype-indep]
#pragma unroll
  for (int i = 0; i < 8; ++i) {
#pragma unroll
    for (int r = 0; r < 4; ++r) {
      int ml = wm + i * 16 + kg * 4 + r;
      int gm = m0 + ml;
      float rs = row_scale[gm];
      float xvv[8];
#pragma unroll
      for (int o = 0; o < 8; ++o) xvv[o] = xsh[ml * 8 + o];
#pragma unroll
      for (int j = 0; j < 4; ++j) {
        int nl = wn + j * 16 + lrow;
        float corr = 0.0f;
#pragma unroll
        for (int o = 0; o < 8; ++o) corr += xvv[o] * wsh[nl * 8 + o];
        for (int o = 8; o < cnt; ++o)   // generality fallback (cold in practice)
          corr += x[(size_t)gm * K_DIM + outlist[o]] *
                  w[(size_t)gn[j] * K_DIM + outlist[o]];
        float val = (float)acc[i][j][r] * rs * qs[j] + corr + bv[j];
        out[(size_t)gm * N_DIM + gn[j]] = val;
      }
    }
  }
}

// ---------------------------------------------------------------------------
extern "C" void kernel_launch(void* const* d_in, const int* in_sizes, int n_in,
                              void* d_out, int out_size, void* d_ws, size_t ws_size,
                              hipStream_t stream) {
  const float* x = (const float*)d_in[0];      // [M,K] fp32 (M = B*S)
  const float* w = (const float*)d_in[1];      // [N,K] fp32
  const float* bias = (const float*)d_in[2];   // [N]
  float* out = (float*)d_out;                  // [M,N] fp32
  const int M = in_sizes[0] / K_DIM;           // 4096

  // workspace layout
  char* ws = (char*)d_ws;
  int* mask = (int*)(ws);                          // 16 KB
  int* count = (int*)(ws + 16384);                 // 4 B (memset region)
  int* outlist = (int*)(ws + 20480);               // 16 KB
  float* row_scale = (float*)(ws + 36864);         // 16 KB
  float* q_scale = (float*)(ws + 53248);           // 16 KB
  int8_t* qx = (int8_t*)(ws + 131072);             // M*K int8 = 16 MB
  int8_t* qw = (int8_t*)(ws + 131072 + (size_t)M * K_DIM);  // N*K int8 = 16 MB

  hipMemsetAsync(ws, 0, 20480, stream);  // mask + count
  k_rowquant<<<M, 256, 0, stream>>>(x, row_scale, mask, qx);
  k_compact<<<K_DIM / 256, 256, 0, stream>>>(mask, outlist, count);
  k_wquant<<<N_DIM, 256, 0, stream>>>(w, mask, q_scale, qw);
  dim3 grid(N_DIM / 256, M / 256);
  k_gemm<<<grid, dim3(512, 1, 1), 0, stream>>>(qx, qw, row_scale, q_scale, bias,
                                               x, w, outlist, count, out);
}

// Round 2
// 246.970 us; speedup vs baseline: 1.0977x; 1.0044x over previous
//
#include <hip/hip_runtime.h>
#include <stdint.h>

#define K_DIM 4096
#define N_DIM 4096
#define SIGMA 20.0f
#define EPSQ 1e-8f

typedef __attribute__((ext_vector_type(4))) int i32x4;

// global_load_lds width-16 helper (addrspace casts: generic->AS1 / ->AS3)
#define GLDS16(gp, lp)                                                         \
  __builtin_amdgcn_global_load_lds(                                            \
      (const __attribute__((address_space(1))) unsigned int*)(const void*)(gp),\
      (__attribute__((address_space(3))) unsigned int*)(void*)(lp), 16, 0, 0)

// ---------------------------------------------------------------------------
// Kernel 1: per-row absmax -> row_scale, outlier column mask, quantize x->int8
// ---------------------------------------------------------------------------
__global__ __launch_bounds__(256) void k_rowquant(
    const float* __restrict__ x, float* __restrict__ row_scale,
    int* __restrict__ mask, int8_t* __restrict__ qx)
{
  const int m = blockIdx.x;
  const int t = threadIdx.x;
  const float4* xr = (const float4*)(x + (size_t)m * K_DIM);
  float4 v[4];
  float amax = 0.0f;
#pragma unroll
  for (int i = 0; i < 4; ++i) {
    v[i] = xr[t + i * 256];
    float a0 = fabsf(v[i].x), a1 = fabsf(v[i].y);
    float a2 = fabsf(v[i].z), a3 = fabsf(v[i].w);
    amax = fmaxf(amax, fmaxf(fmaxf(a0, a1), fmaxf(a2, a3)));
    int kbase = (t + i * 256) * 4;
    if (a0 > SIGMA) mask[kbase + 0] = 1;
    if (a1 > SIGMA) mask[kbase + 1] = 1;
    if (a2 > SIGMA) mask[kbase + 2] = 1;
    if (a3 > SIGMA) mask[kbase + 3] = 1;
  }
#pragma unroll
  for (int off = 32; off > 0; off >>= 1)
    amax = fmaxf(amax, __shfl_down(amax, off, 64));
  __shared__ float smax[4];
  __shared__ float sscale;
  if ((t & 63) == 0) smax[t >> 6] = amax;
  __syncthreads();
  if (t == 0) {
    float ms = fmaxf(fmaxf(smax[0], smax[1]), fmaxf(smax[2], smax[3]));
    float rs = fmaxf(ms / 127.0f, EPSQ);  // IEEE divide: bit-match jnp
    sscale = rs;
    row_scale[m] = rs;
  }
  __syncthreads();
  const float rs = sscale;
  uint32_t* qxo = (uint32_t*)(qx + (size_t)m * K_DIM);
#pragma unroll
  for (int i = 0; i < 4; ++i) {
    int q0 = (int)rintf(fminf(fmaxf(v[i].x / rs, -128.0f), 127.0f));
    int q1 = (int)rintf(fminf(fmaxf(v[i].y / rs, -128.0f), 127.0f));
    int q2 = (int)rintf(fminf(fmaxf(v[i].z / rs, -128.0f), 127.0f));
    int q3 = (int)rintf(fminf(fmaxf(v[i].w / rs, -128.0f), 127.0f));
    uint32_t packed = (uint32_t)(q0 & 0xff) | ((uint32_t)(q1 & 0xff) << 8) |
                      ((uint32_t)(q2 & 0xff) << 16) | ((uint32_t)(q3 & 0xff) << 24);
    qxo[t + i * 256] = packed;
  }
}

// ---------------------------------------------------------------------------
// Kernel 2: weight quant (zero outlier cols, per-row absmax -> q_scale, int8)
// + fused mask compaction (block 0 only; mask is complete at launch since the
// stream serializes after k_rowquant; k_gemm launches after this completes).
// ---------------------------------------------------------------------------
__global__ __launch_bounds__(256) void k_wquant(
    const float* __restrict__ w, const int* __restrict__ mask,
    float* __restrict__ q_scale, int8_t* __restrict__ qw,
    int* __restrict__ outlist, int* __restrict__ count)
{
  const int n = blockIdx.x;
  const int t = threadIdx.x;
  if (n == 0) {
    for (int kk = t; kk < K_DIM; kk += 256) {
      if (mask[kk]) {
        int idx = atomicAdd(count, 1);
        outlist[idx] = kk;
      }
    }
  }
  const float4* wr = (const float4*)(w + (size_t)n * K_DIM);
  const int4* mr = (const int4*)mask;
  float4 v[4];
  float amax = 0.0f;
#pragma unroll
  for (int i = 0; i < 4; ++i) {
    float4 vv = wr[t + i * 256];
    int4 mm = mr[t + i * 256];
    vv.x = mm.x ? 0.0f : vv.x;
    vv.y = mm.y ? 0.0f : vv.y;
    vv.z = mm.z ? 0.0f : vv.z;
    vv.w = mm.w ? 0.0f : vv.w;
    v[i] = vv;
    amax = fmaxf(amax, fmaxf(fmaxf(fabsf(vv.x), fabsf(vv.y)),
                             fmaxf(fabsf(vv.z), fabsf(vv.w))));
  }
#pragma unroll
  for (int off = 32; off > 0; off >>= 1)
    amax = fmaxf(amax, __shfl_down(amax, off, 64));
  __shared__ float smax[4];
  __shared__ float sscale;
  if ((t & 63) == 0) smax[t >> 6] = amax;
  __syncthreads();
  if (t == 0) {
    float ms = fmaxf(fmaxf(smax[0], smax[1]), fmaxf(smax[2], smax[3]));
    float qs = fmaxf(ms / 127.0f, EPSQ);
    sscale = qs;
    q_scale[n] = qs;
  }
  __syncthreads();
  const float qs = sscale;
  uint32_t* qwo = (uint32_t*)(qw + (size_t)n * K_DIM);
#pragma unroll
  for (int i = 0; i < 4; ++i) {
    int q0 = (int)rintf(fminf(fmaxf(v[i].x / qs, -128.0f), 127.0f));
    int q1 = (int)rintf(fminf(fmaxf(v[i].y / qs, -128.0f), 127.0f));
    int q2 = (int)rintf(fminf(fmaxf(v[i].z / qs, -128.0f), 127.0f));
    int q3 = (int)rintf(fminf(fmaxf(v[i].w / qs, -128.0f), 127.0f));
    uint32_t packed = (uint32_t)(q0 & 0xff) | ((uint32_t)(q1 & 0xff) << 8) |
                      ((uint32_t)(q2 & 0xff) << 16) | ((uint32_t)(q3 & 0xff) << 24);
    qwo[t + i * 256] = packed;
  }
}

// ---------------------------------------------------------------------------
// Kernel 3: int8 GEMM, 256x256 tile, BK=64, 8 waves (2Mx4N), 512 threads.
// Counted-vmcnt deep pipeline: 4 LDS tile buffers (128 KB), stage tile t+3
// while computing tile t. ONE s_barrier per K-tile (minimal correct set):
//   - WAR: reads of tile kt are lgkm-drained before iter kt's end barrier;
//     staging into that buffer happens in iter kt+1, after the barrier.
//   - RAW: vmcnt(8) before the barrier guarantees tile kt+1's 4 GLDS landed;
//     barrier makes them visible.
// No mid-phase barriers -> the 2 waves/SIMD slip apart so one wave's
// ds_read/lgkm-wait hides under the other's MFMA cluster (the role-split
// that makes setprio pay). lgkmcnt(0)+sched_barrier(0) per rule #18.
// 64B LDS rows with 2-row-unit XOR chunk swizzle c_phys = c ^ ((row>>1)&3),
// applied on the GLOBAL source side for staging and on LDS read offsets.
// ---------------------------------------------------------------------------
__global__ __launch_bounds__(512, 2) void k_gemm(
    const int8_t* __restrict__ qx, const int8_t* __restrict__ qw,
    const float* __restrict__ row_scale, const float* __restrict__ q_scale,
    const float* __restrict__ bias,
    const float* __restrict__ x, const float* __restrict__ w,
    const int* __restrict__ outlist, const int* __restrict__ outcount,
    float* __restrict__ out)
{
  __shared__ int8_t As[4][256 * 64];   // 4 x 16 KB
  __shared__ int8_t Bs[4][256 * 64];   // 4 x 16 KB   -> 128 KB total

  const int t = threadIdx.x;            // 0..511
  const int m0 = blockIdx.y * 256;
  const int n0 = blockIdx.x * 256;
  const int lane = t & 63;
  const int wave = t >> 6;              // 0..7
  const int wm = (wave >> 2) * 128;     // 0 or 128
  const int wn = (wave & 3) * 64;       // 0,64,128,192
  const int lrow = lane & 15;
  const int kg = lane >> 4;             // 0..3

  i32x4 acc[8][4] = {};

  // staging: thread t covers row t>>2 (0..127 within half-tile), phys chunk t&3
  const int srow = t >> 2;
  const int sclog = (t & 3) ^ ((srow >> 1) & 3);
  const int8_t* gA = qx + (size_t)(m0 + srow) * K_DIM + sclog * 16;
  const int8_t* gB = qw + (size_t)(n0 + srow) * K_DIM + sclog * 16;

  // loop-invariant swizzled LDS read offsets (within one 16 KB tile buffer)
  int offA[8], offB[4];
#pragma unroll
  for (int i = 0; i < 8; ++i) {
    int rA = wm + i * 16 + lrow;
    offA[i] = rA * 64 + ((kg ^ ((rA >> 1) & 3)) * 16);
  }
#pragma unroll
  for (int j = 0; j < 4; ++j) {
    int rB = wn + j * 16 + lrow;
    offB[j] = rB * 64 + ((kg ^ ((rB >> 1) & 3)) * 16);
  }

#define STAGE_A(b, tt) do {                                                    \
    GLDS16(gA + (size_t)(tt) * 64, &As[b][t * 16]);                            \
    GLDS16(gA + (size_t)128 * K_DIM + (size_t)(tt) * 64, &As[b][8192 + t * 16]);\
  } while (0)
#define STAGE_B(b, tt) do {                                                    \
    GLDS16(gB + (size_t)(tt) * 64, &Bs[b][t * 16]);                            \
    GLDS16(gB + (size_t)128 * K_DIM + (size_t)(tt) * 64, &Bs[b][8192 + t * 16]);\
  } while (0)

  // prologue: fill 3 tiles (12 gloads/wave); wait only tile 0 (newest 8 in flight)
  STAGE_A(0, 0); STAGE_B(0, 0);
  STAGE_A(1, 1); STAGE_B(1, 1);
  STAGE_A(2, 2); STAGE_B(2, 2);
  asm volatile("s_waitcnt vmcnt(8)" ::: "memory");
  __builtin_amdgcn_s_barrier();

#pragma unroll 4
  for (int kt = 0; kt < 64; ++kt) {
    const int cur = kt & 3;
    const int nx = (kt + 3) & 3;        // == (kt-1)&3: fully consumed last tile
    const int ktn = (kt + 3) & 63;      // wrap staging keeps vmcnt uniform
    const int8_t* a = &As[cur][0];
    const int8_t* b = &Bs[cur][0];

    // ---- phase 1: read A-top + all B, stage next tile, compute top half ----
    i32x4 af[4], bf[4];
#pragma unroll
    for (int i = 0; i < 4; ++i) af[i] = *(const i32x4*)(a + offA[i]);
#pragma unroll
    for (int j = 0; j < 4; ++j) bf[j] = *(const i32x4*)(b + offB[j]);
    STAGE_A(nx, ktn);
    STAGE_B(nx, ktn);
    asm volatile("s_waitcnt lgkmcnt(0)" ::: "memory");
    __builtin_amdgcn_sched_barrier(0);
    __builtin_amdgcn_s_setprio(1);
#pragma unroll
    for (int i = 0; i < 4; ++i)
#pragma unroll
      for (int j = 0; j < 4; ++j)
        acc[i][j] = __builtin_amdgcn_mfma_i32_16x16x64_i8(af[i], bf[j], acc[i][j], 0, 0, 0);
    __builtin_amdgcn_s_setprio(0);

    // ---- phase 2: read A-bot (B reused in regs), compute bottom half ----
    i32x4 af2[4];
#pragma unroll
    for (int i = 0; i < 4; ++i) af2[i] = *(const i32x4*)(a + offA[4 + i]);
    asm volatile("s_waitcnt lgkmcnt(0)" ::: "memory");
    __builtin_amdgcn_sched_barrier(0);
    __builtin_amdgcn_s_setprio(1);
#pragma unroll
    for (int i = 0; i < 4; ++i)
#pragma unroll
      for (int j = 0; j < 4; ++j)
        acc[4 + i][j] = __builtin_amdgcn_mfma_i32_16x16x64_i8(af2[i], bf[j], acc[4 + i][j], 0, 0, 0);
    __builtin_amdgcn_s_setprio(0);

    // counted wait: tiles kt+2,kt+3 (8 loads) stay in flight; kt+1 is ready
    asm volatile("s_waitcnt vmcnt(8)" ::: "memory");
    __builtin_amdgcn_s_barrier();
  }

#undef STAGE_A
#undef STAGE_B

  // ---- epilogue: stage outlier x / w slices into LDS (reuse buffer 0) ----
  __syncthreads();  // full drain (vmcnt 0 + lgkm 0 + barrier): wrap gloads land
  float* xsh = (float*)&As[0][0];   // [256][8]
  float* wsh = (float*)&Bs[0][0];   // [256][8]
  const int cnt = *outcount;
  const int cs = cnt < 8 ? cnt : 8;
#pragma unroll
  for (int u = 0; u < 4; ++u) {
    int idx = t * 4 + u;   // 0..2047
    int rr = idx >> 3;     // 0..255
    int oo = idx & 7;
    float xv = 0.0f, wv = 0.0f;
    if (oo < cs) {
      int kcol = outlist[oo];
      xv = x[(size_t)(m0 + rr) * K_DIM + kcol];
      wv = w[(size_t)(n0 + rr) * K_DIM + kcol];
    }
    xsh[rr * 8 + oo] = xv;
    wsh[rr * 8 + oo] = wv;
  }
  __syncthreads();

  float qs[4], bv[4];
  int gn[4];
#pragma unroll
  for (int j = 0; j < 4; ++j) {
    gn[j] = n0 + wn + j * 16 + lrow;
    qs[j] = q_scale[gn[j]];
    bv[j] = bias[gn[j]];
  }

  // C/D layout: col = lane&15, row = (lane>>4)*4 + reg  [m89/m101, dtype-indep]
#pragma unroll
  for (int i = 0; i < 8; ++i) {
#pragma unroll
    for (int r = 0; r < 4; ++r) {
      int ml = wm + i * 16 + kg * 4 + r;
      int gm = m0 + ml;
      float rs = row_scale[gm];
      float xvv[8];
#pragma unroll
      for (int o = 0; o < 8; ++o) xvv[o] = xsh[ml * 8 + o];
#pragma unroll
      for (int j = 0; j < 4; ++j) {
        int nl = wn + j * 16 + lrow;
        float corr = 0.0f;
#pragma unroll
        for (int o = 0; o < 8; ++o) corr += xvv[o] * wsh[nl * 8 + o];
        for (int o = 8; o < cnt; ++o)   // generality fallback (cold in practice)
          corr += x[(size_t)gm * K_DIM + outlist[o]] *
                  w[(size_t)gn[j] * K_DIM + outlist[o]];
        float val = (float)acc[i][j][r] * rs * qs[j] + corr + bv[j];
        out[(size_t)gm * N_DIM + gn[j]] = val;
      }
    }
  }
}

// ---------------------------------------------------------------------------
extern "C" void kernel_launch(void* const* d_in, const int* in_sizes, int n_in,
                              void* d_out, int out_size, void* d_ws, size_t ws_size,
                              hipStream_t stream) {
  const float* x = (const float*)d_in[0];      // [M,K] fp32 (M = B*S)
  const float* w = (const float*)d_in[1];      // [N,K] fp32
  const float* bias = (const float*)d_in[2];   // [N]
  float* out = (float*)d_out;                  // [M,N] fp32
  const int M = in_sizes[0] / K_DIM;           // 4096

  // workspace layout
  char* ws = (char*)d_ws;
  int* mask = (int*)(ws);                          // 16 KB
  int* count = (int*)(ws + 16384);                 // 4 B (memset region)
  int* outlist = (int*)(ws + 20480);               // 16 KB
  float* row_scale = (float*)(ws + 36864);         // 16 KB
  float* q_scale = (float*)(ws + 53248);           // 16 KB
  int8_t* qx = (int8_t*)(ws + 131072);             // M*K int8 = 16 MB
  int8_t* qw = (int8_t*)(ws + 131072 + (size_t)M * K_DIM);  // N*K int8 = 16 MB

  hipMemsetAsync(ws, 0, 20480, stream);  // mask + count
  k_rowquant<<<M, 256, 0, stream>>>(x, row_scale, mask, qx);
  k_wquant<<<N_DIM, 256, 0, stream>>>(w, mask, q_scale, qw, outlist, count);
  dim3 grid(N_DIM / 256, M / 256);
  k_gemm<<<grid, dim3(512, 1, 1), 0, stream>>>(qx, qw, row_scale, q_scale, bias,
                                               x, w, outlist, count, out);
}